// Round 1
// baseline (630.818 us; speedup 1.0000x reference)
//
#include <hip/hip_runtime.h>
#include <hip/hip_bf16.h>
#include <stdint.h>

#define HIDDEN  1024
#define FFN     3584
#define NE      8
#define NTOK    2048
#define CAP     2048
#define OUT_ELEMS (NTOK * HIDDEN)   /* 2097152 */

/* ---- workspace layout (bytes) ---- */
#define X_OFF   0u                          /* x as bf16: 2048*1024*2 = 4 MiB   */
#define CNT_OFF (4u*1024u*1024u)            /* 8 int counters                   */
#define TOK_OFF (CNT_OFF + 256u)            /* token lists: 8*2048*4 = 64 KiB   */
#define WGT_OFF (TOK_OFF + 65536u)          /* combine weights: 64 KiB          */
#define ACT_OFF (WGT_OFF + 65536u)          /* packed act bf16: 4096*3584*2     */

typedef __attribute__((ext_vector_type(8))) short short8;
typedef __attribute__((ext_vector_type(4))) float floatx4;

static __device__ __forceinline__ uint32_t f2bf(float f) {
  union { float f; uint32_t u; } v; v.f = f;
  return (v.u + 0x7FFFu + ((v.u >> 16) & 1u)) >> 16;   /* RNE */
}
static __device__ __forceinline__ uint32_t pack2(float lo, float hi) {
  return f2bf(lo) | (f2bf(hi) << 16);
}
union S8U { uint4 u; short8 s; };
static __device__ __forceinline__ short8 as_short8(uint4 v) { S8U x; x.u = v; return x.s; }

/* ---- zero output accumulation region + expert counters ---- */
__global__ __launch_bounds__(256) void moe_prep(float4* __restrict__ out4,
                                                int* __restrict__ cnt) {
  uint32_t i = blockIdx.x * 256u + threadIdx.x;   /* 2048 blocks -> 524288 float4 */
  out4[i] = make_float4(0.f, 0.f, 0.f, 0.f);
  if (blockIdx.x == 0 && threadIdx.x < NE) cnt[threadIdx.x] = 0;
}

/* ---- x fp32 -> bf16 ---- */
__global__ __launch_bounds__(256) void moe_convert(const float4* __restrict__ x4,
                                                   uint4* __restrict__ xb) {
  uint32_t g = blockIdx.x * 256u + threadIdx.x;   /* 1024 blocks, 8 floats each */
  float4 a = x4[2u*g], b = x4[2u*g + 1u];
  xb[g] = make_uint4(pack2(a.x, a.y), pack2(a.z, a.w),
                     pack2(b.x, b.y), pack2(b.z, b.w));
}

/* ---- router: one wave per token ---- */
__global__ __launch_bounds__(256) void moe_router(
    const float* __restrict__ x, const float* __restrict__ gw,
    float* __restrict__ logits, int* __restrict__ cnt,
    int* __restrict__ tok, float* __restrict__ wgt)
{
  const int t = blockIdx.x * 4 + (threadIdx.x >> 6);
  const int lane = threadIdx.x & 63;
  const float* xr = x + (size_t)t * HIDDEN;
  float a[NE];
#pragma unroll
  for (int e = 0; e < NE; ++e) a[e] = 0.f;
  for (int hh = 0; hh < HIDDEN / 64; ++hh) {
    float xv = xr[hh * 64 + lane];
#pragma unroll
    for (int e = 0; e < NE; ++e) a[e] += xv * gw[e * HIDDEN + hh * 64 + lane];
  }
#pragma unroll
  for (int off = 32; off > 0; off >>= 1) {
#pragma unroll
    for (int e = 0; e < NE; ++e) a[e] += __shfl_xor(a[e], off);
  }
  if (lane == 0) {
#pragma unroll
    for (int e = 0; e < NE; ++e) logits[t * NE + e] = a[e];
    int i0 = 0; float v0 = a[0];
#pragma unroll
    for (int e = 1; e < NE; ++e) if (a[e] > v0) { v0 = a[e]; i0 = e; }
    int i1 = (i0 == 0) ? 1 : 0; float v1 = a[i1];
#pragma unroll
    for (int e = 0; e < NE; ++e) if (e != i0 && a[e] > v1) { v1 = a[e]; i1 = e; }
    /* renormalized top-2 weights: ratio of softmax probs, sum-independent */
    float w0 = 1.f / (1.f + __expf(v1 - v0));
    float w1 = 1.f - w0;
    int p0 = atomicAdd(&cnt[i0], 1); tok[i0 * CAP + p0] = t; wgt[i0 * CAP + p0] = w0;
    int p1 = atomicAdd(&cnt[i1], 1); tok[i1 * CAP + p1] = t; wgt[i1 * CAP + p1] = w1;
  }
}

/* ==== grouped GEMM 1: act = silu(x@Wg) * (x@Wu), gathered rows, BM=128 BN(gate)=64 BK=64 ==== */
__global__ __launch_bounds__(256) void moe_gateup(
    const uint4* __restrict__ xb, const float* __restrict__ wgu,
    const int* __restrict__ cnt, const int* __restrict__ tok,
    unsigned short* __restrict__ act)
{
  const int e  = blockIdx.z;
  const int m0 = blockIdx.y * 128;
  const int f0 = blockIdx.x * 64;
  const int cn = cnt[e];
  if (m0 >= cn) return;
  int basev = 0;
#pragma unroll
  for (int i = 0; i < NE; ++i) { int ci = cnt[i]; if (i < e) basev += ci; }

  __shared__ uint4    As[1024];   /* 128 rows x 8 chunks(16B), chunk ^= row&7      */
  __shared__ uint32_t Bs[4096];   /* word(kp,n) = {bf16(2kp),bf16(2kp+1)}, n^=swz  */

  const int tid  = threadIdx.x;
  const int lane = tid & 63;
  const int w    = tid >> 6;
  const int wm   = w >> 1, wn = w & 1;
  const int q    = lane >> 4;
  const int c    = lane & 15;

  floatx4 acc[4][4];
#pragma unroll
  for (int i = 0; i < 4; ++i)
#pragma unroll
    for (int j = 0; j < 4; ++j) acc[i][j] = (floatx4){0.f, 0.f, 0.f, 0.f};

  const float* wB  = wgu + (size_t)e * HIDDEN * (2 * FFN);
  const int* tokE  = tok + e * CAP;

  for (int kt = 0; kt < HIDDEN / 64; ++kt) {
    const int k0 = kt * 64;
    __syncthreads();
    /* A: gathered x rows (bf16), 1024 chunks */
#pragma unroll
    for (int it = 0; it < 4; ++it) {
      int cid = it * 256 + tid;
      int row = cid >> 3, c8 = cid & 7;
      int mrow = m0 + row; if (mrow >= cn) mrow = cn - 1;
      int tk = tokE[mrow];
      As[row * 8 + (c8 ^ (row & 7))] = xb[(size_t)tk * (HIDDEN / 8) + (k0 >> 3) + c8];
    }
    /* B: fp32 [K][N] -> bf16 k-paired words; n<64 gate-cols, n>=... interleaved per wave */
#pragma unroll
    for (int it = 0; it < 4; ++it) {
      int mid = it * 256 + tid;
      int kp = mid >> 5;
      int n  = (mid & 31) * 4;
      int col = f0 + ((n >> 6) << 5) + (n & 31) + (((n >> 5) & 1) ? FFN : 0);
      const float* src = wB + (size_t)(k0 + 2 * kp) * (2 * FFN) + col;
      float4 r0 = *(const float4*)src;
      float4 r1 = *(const float4*)(src + 2 * FFN);
      int widx = kp * 128 + (n ^ (((kp >> 2) & 1) << 4));
      *(uint4*)&Bs[widx] = make_uint4(pack2(r0.x, r1.x), pack2(r0.y, r1.y),
                                      pack2(r0.z, r1.z), pack2(r0.w, r1.w));
    }
    __syncthreads();
#pragma unroll
    for (int ks = 0; ks < 2; ++ks) {
      short8 af[4];
#pragma unroll
      for (int i = 0; i < 4; ++i) {
        int row = wm * 64 + i * 16 + c;
        int kc8 = ks * 4 + q;
        af[i] = as_short8(As[row * 8 + (kc8 ^ (row & 7))]);
      }
      short8 bfr[4];
#pragma unroll
      for (int j = 0; j < 4; ++j) {
        int n  = wn * 64 + j * 16 + c;
        int kp = ks * 16 + q * 4;
        int nn = n ^ ((q & 1) << 4);
        bfr[j] = as_short8(make_uint4(Bs[(kp + 0) * 128 + nn], Bs[(kp + 1) * 128 + nn],
                                      Bs[(kp + 2) * 128 + nn], Bs[(kp + 3) * 128 + nn]));
      }
#pragma unroll
      for (int i = 0; i < 4; ++i)
#pragma unroll
        for (int j = 0; j < 4; ++j)
          acc[i][j] = __builtin_amdgcn_mfma_f32_16x16x32_bf16(af[i], bfr[j], acc[i][j], 0, 0, 0);
    }
  }

  /* epilogue: silu(gate)*up, bf16 store to packed act rows (frag j pairs with j+2) */
#pragma unroll
  for (int i = 0; i < 4; ++i) {
#pragma unroll
    for (int r = 0; r < 4; ++r) {
      int m = m0 + wm * 64 + i * 16 + q * 4 + r;
      if (m < cn) {
#pragma unroll
        for (int j = 0; j < 2; ++j) {
          float g = acc[i][j][r];
          float u = acc[i][j + 2][r];
          float a = (g / (1.f + __expf(-g))) * u;
          act[(size_t)(basev + m) * FFN + (f0 + wn * 32 + j * 16 + c)] = (unsigned short)f2bf(a);
        }
      }
    }
  }
}

/* ==== grouped GEMM 2: out[t] += w * (act @ Wdown), BM=128 BN=128 BK=64 ==== */
__global__ __launch_bounds__(256) void moe_down(
    const uint4* __restrict__ actc, const float* __restrict__ wd,
    const int* __restrict__ cnt, const int* __restrict__ tok,
    const float* __restrict__ wgt, float* __restrict__ out)
{
  const int e  = blockIdx.z;
  const int m0 = blockIdx.y * 128;
  const int n0 = blockIdx.x * 128;
  const int cn = cnt[e];
  if (m0 >= cn) return;
  int basev = 0;
#pragma unroll
  for (int i = 0; i < NE; ++i) { int ci = cnt[i]; if (i < e) basev += ci; }

  __shared__ uint4    As[1024];
  __shared__ uint32_t Bs[4096];

  const int tid  = threadIdx.x;
  const int lane = tid & 63;
  const int w    = tid >> 6;
  const int wm   = w >> 1, wn = w & 1;
  const int q    = lane >> 4;
  const int c    = lane & 15;

  floatx4 acc[4][4];
#pragma unroll
  for (int i = 0; i < 4; ++i)
#pragma unroll
    for (int j = 0; j < 4; ++j) acc[i][j] = (floatx4){0.f, 0.f, 0.f, 0.f};

  const float* wB = wd + (size_t)e * FFN * HIDDEN;

  for (int kt = 0; kt < FFN / 64; ++kt) {
    const int k0 = kt * 64;
    __syncthreads();
#pragma unroll
    for (int it = 0; it < 4; ++it) {
      int cid = it * 256 + tid;
      int row = cid >> 3, c8 = cid & 7;
      int mrow = m0 + row; if (mrow >= cn) mrow = cn - 1;
      As[row * 8 + (c8 ^ (row & 7))] =
          actc[(size_t)(basev + mrow) * (FFN / 8) + (k0 >> 3) + c8];
    }
#pragma unroll
    for (int it = 0; it < 4; ++it) {
      int mid = it * 256 + tid;
      int kp = mid >> 5;
      int n  = (mid & 31) * 4;
      int col = n0 + n;
      const float* src = wB + (size_t)(k0 + 2 * kp) * HIDDEN + col;
      float4 r0 = *(const float4*)src;
      float4 r1 = *(const float4*)(src + HIDDEN);
      int widx = kp * 128 + (n ^ (((kp >> 2) & 1) << 4));
      *(uint4*)&Bs[widx] = make_uint4(pack2(r0.x, r1.x), pack2(r0.y, r1.y),
                                      pack2(r0.z, r1.z), pack2(r0.w, r1.w));
    }
    __syncthreads();
#pragma unroll
    for (int ks = 0; ks < 2; ++ks) {
      short8 af[4];
#pragma unroll
      for (int i = 0; i < 4; ++i) {
        int row = wm * 64 + i * 16 + c;
        int kc8 = ks * 4 + q;
        af[i] = as_short8(As[row * 8 + (kc8 ^ (row & 7))]);
      }
      short8 bfr[4];
#pragma unroll
      for (int j = 0; j < 4; ++j) {
        int n  = wn * 64 + j * 16 + c;
        int kp = ks * 16 + q * 4;
        int nn = n ^ ((q & 1) << 4);
        bfr[j] = as_short8(make_uint4(Bs[(kp + 0) * 128 + nn], Bs[(kp + 1) * 128 + nn],
                                      Bs[(kp + 2) * 128 + nn], Bs[(kp + 3) * 128 + nn]));
      }
#pragma unroll
      for (int i = 0; i < 4; ++i)
#pragma unroll
        for (int j = 0; j < 4; ++j)
          acc[i][j] = __builtin_amdgcn_mfma_f32_16x16x32_bf16(af[i], bfr[j], acc[i][j], 0, 0, 0);
    }
  }

  /* epilogue: scale by combine weight, scatter-add into output */
#pragma unroll
  for (int i = 0; i < 4; ++i) {
#pragma unroll
    for (int r = 0; r < 4; ++r) {
      int m = m0 + wm * 64 + i * 16 + q * 4 + r;
      if (m < cn) {
        int   t  = tok[e * CAP + m];
        float wg = wgt[e * CAP + m];
        float* orow = out + (size_t)t * HIDDEN + n0 + wn * 64 + c;
#pragma unroll
        for (int j = 0; j < 4; ++j)
          atomicAdd(orow + j * 16, acc[i][j][r] * wg);
      }
    }
  }
}

extern "C" void kernel_launch(void* const* d_in, const int* in_sizes, int n_in,
                              void* d_out, int out_size, void* d_ws, size_t ws_size,
                              hipStream_t stream)
{
  (void)in_sizes; (void)n_in; (void)out_size; (void)ws_size;
  const float* x   = (const float*)d_in[0];
  const float* gw  = (const float*)d_in[1];
  const float* wgu = (const float*)d_in[2];
  const float* wd  = (const float*)d_in[3];
  float* out = (float*)d_out;
  char*  ws  = (char*)d_ws;

  uint4*          xb  = (uint4*)(ws + X_OFF);
  int*            cnt = (int*)(ws + CNT_OFF);
  int*            tok = (int*)(ws + TOK_OFF);
  float*          wgt = (float*)(ws + WGT_OFF);
  unsigned short* act = (unsigned short*)(ws + ACT_OFF);

  moe_prep<<<OUT_ELEMS / (256 * 4), 256, 0, stream>>>((float4*)out, cnt);
  moe_convert<<<(NTOK * HIDDEN) / (256 * 8), 256, 0, stream>>>((const float4*)x, xb);
  moe_router<<<NTOK / 4, 256, 0, stream>>>(x, gw, out + OUT_ELEMS, cnt, tok, wgt);
  moe_gateup<<<dim3(FFN / 64, 16, NE), 256, 0, stream>>>(xb, wgu, cnt, tok, act);
  moe_down<<<dim3(HIDDEN / 128, 16, NE), 256, 0, stream>>>((const uint4*)act, wd, cnt, tok, wgt, out);
}